// Round 9
// baseline (83.877 us; speedup 1.0000x reference)
//
#include <hip/hip_runtime.h>

// Problem constants (match reference)
constexpr int B = 128;
constexpr int N = 16384;
constexpr int H = 512;
constexpr int W = 512;
constexpr int HW = H * W;                        // 262144
constexpr long long TOT = (long long)B * HW;     // 33554432 pixels

constexpr int TROWS = 16;                        // rows per tile
constexpr int NTILES = H / TROWS;                // 32 tiles per frame
constexpr int NBUCKETS = B * NTILES;             // 4096
constexpr int CAP = 1024;                        // slots per bucket (mean ~545)
constexpr int NGROUPS = B * N / 4;               // 524288 groups of 4 points
constexpr int BIN_BLOCKS = NGROUPS / 512;        // 1024
constexpr int TPITCH = 520;                      // padded pitch (bank spread)
constexpr int TILE_WORDS = TROWS * TPITCH;       // 8320 floats = 33280 B
constexpr int TPB = 4;                           // tiles per persistent block
constexpr int TILE_BLOCKS = NBUCKETS / TPB;      // 1024 = 4 blocks/CU exactly

__device__ __forceinline__ void lds_add(float* p, float v) {
    __hip_atomic_fetch_add(p, v, __ATOMIC_RELAXED, __HIP_MEMORY_SCOPE_WORKGROUP);
}

// barrier that drains LDS ops but leaves global loads IN FLIGHT (no vmcnt drain)
__device__ __forceinline__ void BAR() {
    asm volatile("s_waitcnt lgkmcnt(0)" ::: "memory");
    __builtin_amdgcn_s_barrier();
}

// ---------------------------------------------------------------------------
// Kernel 0: zero the 4096 bucket counters
// ---------------------------------------------------------------------------
__global__ void __launch_bounds__(512) k_zero(unsigned int* __restrict__ cnt) {
    cnt[blockIdx.x * 512 + threadIdx.x] = 0u;
}

// ---------------------------------------------------------------------------
// Kernel 1: bin points by (frame, row-tile), per-block LDS slot aggregation.
// ---------------------------------------------------------------------------
__global__ void __launch_bounds__(512) k_bin(const float4* __restrict__ pts,
                                             float4* __restrict__ buckets,
                                             unsigned int* __restrict__ cnt) {
    __shared__ unsigned int lcnt[NTILES];
    __shared__ unsigned int lbase[NTILES];

    int tid = blockIdx.x * 512 + threadIdx.x;    // one group of 4 points
    int frame = tid >> 12;                       // 4096 groups per frame
    int fb = frame * NTILES;

    if (threadIdx.x < NTILES) lcnt[threadIdx.x] = 0;
    __syncthreads();

    float4 a = pts[tid * 3 + 0];   // x0 y0 i0 x1
    float4 b = pts[tid * 3 + 1];   // y1 i1 x2 y2
    float4 c = pts[tid * 3 + 2];   // i2 x3 y3 i3

    float xs[4] = {a.x, a.w, b.z, c.y};
    float ys[4] = {a.y, b.x, b.w, c.z};
    float is[4] = {a.z, b.y, c.x, c.w};

    int tb0[4], sl0[4], tb1[4], sl1[4];
#pragma unroll
    for (int k = 0; k < 4; ++k) {
        float x = fminf(fmaxf(xs[k], 0.0f), (float)(W - 1));
        float y = fminf(fmaxf(ys[k], 0.0f), (float)(H - 1));
        xs[k] = x; ys[k] = y;
        int y0 = (int)floorf(y);
        int y1 = min(y0 + 1, H - 1);
        int t0 = y0 >> 4;                         // TROWS = 16
        int t1 = y1 >> 4;
        tb0[k] = t0;
        sl0[k] = (int)atomicAdd(&lcnt[t0], 1u);
        if (t1 != t0) {
            tb1[k] = t1;
            sl1[k] = (int)atomicAdd(&lcnt[t1], 1u);
        } else {
            tb1[k] = -1; sl1[k] = 0;
        }
    }
    __syncthreads();

    if (threadIdx.x < NTILES)
        lbase[threadIdx.x] = atomicAdd(&cnt[fb + threadIdx.x], lcnt[threadIdx.x]);
    __syncthreads();

#pragma unroll
    for (int k = 0; k < 4; ++k) {
        float4 rec = make_float4(xs[k], ys[k], is[k], 0.0f);
        unsigned s0 = lbase[tb0[k]] + (unsigned)sl0[k];
        if (s0 < (unsigned)CAP)
            buckets[(size_t)(fb + tb0[k]) * CAP + s0] = rec;
        if (tb1[k] >= 0) {
            unsigned s1 = lbase[tb1[k]] + (unsigned)sl1[k];
            if (s1 < (unsigned)CAP)
                buckets[(size_t)(fb + tb1[k]) * CAP + s1] = rec;
        }
    }
}

// ---------------------------------------------------------------------------
// Kernel 2: persistent block, 4 tiles sequentially, software-pipelined:
// tile j+1's global loads issue during tile j's phases and are consumed a
// phase later; barriers drain LDS only (loads stay in flight).
// ---------------------------------------------------------------------------
__device__ __forceinline__ void splat(float4 p, float* __restrict__ tile, int r0) {
    float x = p.x, y = p.y, inten = p.z;         // clamped at bin time
    float x0f = floorf(x), y0f = floorf(y);
    float fx = x - x0f, fy = y - y0f;
    int x0 = (int)x0f, y0 = (int)y0f;
    int x1 = min(x0 + 1, W - 1);
    int y1 = min(y0 + 1, H - 1);
    int ra = y0 - r0;
    int rb = y1 - r0;
    float w00 = inten * (1.0f - fx) * (1.0f - fy);
    float w01 = inten * fx * (1.0f - fy);
    float w10 = inten * (1.0f - fx) * fy;
    float w11 = inten * fx * fy;
    if ((unsigned)ra < (unsigned)TROWS) {
        lds_add(&tile[ra * TPITCH + x0], w00);
        lds_add(&tile[ra * TPITCH + x1], w01);
    }
    if ((unsigned)rb < (unsigned)TROWS) {
        lds_add(&tile[rb * TPITCH + x0], w10);
        lds_add(&tile[rb * TPITCH + x1], w11);
    }
}

__global__ void __launch_bounds__(512) k_tile(const float4* __restrict__ buckets,
                                              const unsigned int* __restrict__ cnt,
                                              const float* __restrict__ tgt,
                                              double* __restrict__ ptile) {
    __shared__ __align__(16) float tile[TILE_WORDS];   // 33280 B
    __shared__ double sacc[8];
    int tid = threadIdx.x;
    int base = blockIdx.x * TPB;

    float4 P[2][2];      // bucket slots, double-buffered
    float4 TV[2][4];     // target pixels, double-buffered
    int    NN[2];        // bucket counts

#define LOADT(slot, tj) do {                                                   \
        int tid_ = base + (tj);                                                \
        const float4* bp_ = buckets + (size_t)tid_ * CAP;                      \
        P[slot][0] = bp_[tid];                                                 \
        P[slot][1] = bp_[tid + 512];                                           \
        const float4* tg_ = (const float4*)(tgt + (size_t)(tid_ >> 5) * HW +   \
                                            (size_t)(tid_ & 31) * TROWS * W);  \
        TV[slot][0] = tg_[tid];                                                \
        TV[slot][1] = tg_[tid + 512];                                          \
        TV[slot][2] = tg_[tid + 1024];                                         \
        TV[slot][3] = tg_[tid + 1536];                                         \
        NN[slot] = (int)min(cnt[tid_], (unsigned)CAP);                         \
    } while (0)

    LOADT(0, 0);                                 // prologue: tile 0 in flight

    float4* t4 = (float4*)tile;
#pragma unroll
    for (int j = 0; j < TPB; ++j) {
        const int cur = j & 1, nxt = cur ^ 1;
        int tile_id = base + j;
        int r0 = (tile_id & (NTILES - 1)) * TROWS;

        // ---- zero LDS tile ----
        float4 z = make_float4(0.f, 0.f, 0.f, 0.f);
        for (int i = tid; i < TILE_WORDS / 4; i += 512)
            t4[i] = z;

        // ---- issue next tile's loads (consumed next iteration) ----
        if (j + 1 < TPB) LOADT(nxt, j + 1);

        BAR();                                   // zero visible; loads fly on

        // ---- splat (vmcnt wait here covers only THIS tile's loads) ----
        int n = NN[cur];
        if (tid < n)       splat(P[cur][0], tile, r0);
        if (tid + 512 < n) splat(P[cur][1], tile, r0);

        BAR();                                   // atomics visible

        // ---- (img - tgt)^2 from registers ----
        float facc = 0.0f;
#pragma unroll
        for (int k = 0; k < 4; ++k) {
            int g = tid + k * 512;               // float4 index in 512-col space
            int r = g >> 7;
            int c = (g & 127) << 2;
            float4 sv = *(const float4*)&tile[r * TPITCH + c];
            float4 tv = TV[cur][k];
            float d0 = sv.x - tv.x, d1 = sv.y - tv.y;
            float d2 = sv.z - tv.z, d3 = sv.w - tv.w;
            facc += d0 * d0 + d1 * d1 + d2 * d2 + d3 * d3;
        }

        // ---- block reduction ----
        for (int off = 32; off > 0; off >>= 1)
            facc += __shfl_down(facc, off, 64);
        int lane = tid & 63;
        int wave = tid >> 6;
        if (lane == 0) sacc[wave] = (double)facc;
        BAR();                                   // sacc visible; tile reads drained
        if (tid == 0) {
            double s = 0.0;
#pragma unroll
            for (int wv = 0; wv < 8; ++wv) s += sacc[wv];
            ptile[tile_id] = s;
        }
        // next iteration's zero is safe: all waves drained their tile reads
        // at the BAR above; sacc is only re-written after two more BARs.
    }
#undef LOADT
}

// ---------------------------------------------------------------------------
// Kernel 3: final reduce of NBUCKETS partials -> mean -> d_out[0]
// ---------------------------------------------------------------------------
__global__ void __launch_bounds__(512) k_final(const double* __restrict__ ptile,
                                               float* __restrict__ out) {
    double acc = 0.0;
    for (int i = threadIdx.x; i < NBUCKETS; i += 512)
        acc += ptile[i];
    for (int off = 32; off > 0; off >>= 1)
        acc += __shfl_down(acc, off, 64);
    __shared__ double sacc[8];
    int lane = threadIdx.x & 63;
    int wave = threadIdx.x >> 6;
    if (lane == 0) sacc[wave] = acc;
    __syncthreads();
    if (threadIdx.x == 0) {
        double s = 0.0;
#pragma unroll
        for (int wv = 0; wv < 8; ++wv) s += sacc[wv];
        out[0] = (float)(s / (double)TOT);
    }
}

// ---------------------------------------------------------------------------
extern "C" void kernel_launch(void* const* d_in, const int* in_sizes, int n_in,
                              void* d_out, int out_size, void* d_ws, size_t ws_size,
                              hipStream_t stream) {
    const float* pts = (const float*)d_in[0];     // [B, N, 3]
    const float* tgt = (const float*)d_in[1];     // [B, H, W]
    float* out = (float*)d_out;

    // ws layout: [ cnt 16KB | ptile 32KB | pad to 64KB | buckets 64MiB ]
    unsigned int* cnt = (unsigned int*)d_ws;
    double* ptile = (double*)((char*)d_ws + 16384);
    float4* buckets = (float4*)((char*)d_ws + 65536);

    k_zero<<<NBUCKETS / 512, 512, 0, stream>>>(cnt);
    k_bin<<<BIN_BLOCKS, 512, 0, stream>>>((const float4*)pts, buckets, cnt);
    k_tile<<<TILE_BLOCKS, 512, 0, stream>>>(buckets, cnt, tgt, ptile);
    k_final<<<1, 512, 0, stream>>>(ptile, out);
}